// Round 9
// baseline (292.350 us; speedup 1.0000x reference)
//
#include <hip/hip_runtime.h>
#include <hip/hip_bf16.h>

// Problem: B=4, T=2048, DIM=1024, H=16, DH=64.  fp32 in/out, bf16 MFMA inside.
// qkv col o = d*48 + kk*16 + h (d outermost, h innermost).

typedef __attribute__((ext_vector_type(8))) short short8;
typedef __attribute__((ext_vector_type(4))) float floatx4;
typedef __attribute__((ext_vector_type(16))) float floatx16;

static __device__ __forceinline__ floatx4 mfma16(short8 a, short8 b, floatx4 c) {
    return __builtin_amdgcn_mfma_f32_16x16x32_bf16(a, b, c, 0, 0, 0);
}
static __device__ __forceinline__ floatx16 mfma32(short8 a, short8 b, floatx16 c) {
    return __builtin_amdgcn_mfma_f32_32x32x16_bf16(a, b, c, 0, 0, 0);
}

static __device__ __forceinline__ unsigned short f2bf_bits(float f) {
    __hip_bfloat16 h = __float2bfloat16(f);
    return *reinterpret_cast<unsigned short*>(&h);
}

static __device__ __forceinline__ float fast_exp2(float x) {
#if __has_builtin(__builtin_amdgcn_exp2f)
    return __builtin_amdgcn_exp2f(x);
#else
    return exp2f(x);
#endif
}

// pack two f32 -> one u32 of 2 bf16 (lo in [15:0], hi in [31:16])
static __device__ __forceinline__ unsigned cvt_pk_bf16(float lo, float hi) {
    unsigned r;
    asm("v_cvt_pk_bf16_f32 %0, %1, %2" : "=v"(r) : "v"(lo), "v"(hi));
    return r;
}

// m214-verified idiom: swap(pk(p0,p1), pk(p4,p5)) -> both outputs usable.
static __device__ __forceinline__ void plane32_swap(unsigned& x, unsigned& y) {
#if __has_builtin(__builtin_amdgcn_permlane32_swap)
    typedef unsigned int uintx2 __attribute__((ext_vector_type(2)));
    uintx2 r = __builtin_amdgcn_permlane32_swap(x, y, false, false);
    x = r[0];
    y = r[1];
#else
    asm volatile("v_permlane32_swap_b32 %0, %1" : "+v"(x), "+v"(y));
#endif
}

// async global->LDS, 16 B per lane; LDS dest = wave-uniform base + lane*16
#define GLD16(gptr, ldsptr)                                                  \
    __builtin_amdgcn_global_load_lds(                                        \
        (const __attribute__((address_space(1))) void*)(gptr),               \
        (__attribute__((address_space(3))) void*)(ldsptr), 16, 0, 0)

// ---------------------------------------------------------------------------
// Kernel 0: fp32 -> bf16 conversion (three launches — verified).
// ---------------------------------------------------------------------------
__global__ __launch_bounds__(256) void k_cvt(
    const float* __restrict__ src, unsigned short* __restrict__ dst, int n4)
{
    typedef __attribute__((ext_vector_type(4))) unsigned short ushort4v;
    for (int i = blockIdx.x * blockDim.x + threadIdx.x; i < n4;
         i += gridDim.x * blockDim.x) {
        const float4 v = ((const float4*)src)[i];
        ushort4v o;
        o.x = f2bf_bits(v.x);
        o.y = f2bf_bits(v.y);
        o.z = f2bf_bits(v.z);
        o.w = f2bf_bits(v.w);
        ((ushort4v*)dst)[i] = o;
    }
}

// ---------------------------------------------------------------------------
// Kernel 1: QKV projection.  NEW this round: block tile 256x128, 4 waves,
// WAVE TILE 128x64 (acc[8][4]).  Rationale: the 64x64 wave tile fed 16 MFMA
// (~77 cyc) with 12 LDS ops (~144 cyc) -> LDS-pipe-bound at MfmaUtil~30.
// 128x64 feeds 32 MFMA (~155 cyc) with 18 LDS ops (~216 cyc): ratio 1.9->1.4
// and staging bytes per output element halved.  2-phase dbuf + XCD-chunked
// swizzle kept from the verified r2 family.  Epilogues mechanically extended
// (mi 0..7; Q/K transpose buffer [256][72] = 36 KB).
// ---------------------------------------------------------------------------
__global__ __launch_bounds__(256, 2) void k_qkv(
    const unsigned short* __restrict__ x,   // [8192][1024] bf16
    const unsigned short* __restrict__ wq,  // [3072][1024] bf16
    unsigned short* __restrict__ qb,        // [64 bh][2048 t][64 d]
    unsigned short* __restrict__ kb,        // [64 bh][2048 t][64 d]
    unsigned short* __restrict__ vb)        // [64 bh][64 d][2048 t]
{
    // buffer: A [256][32] @0 (8192 sh) + B [128][32] @8192 (4096 sh);
    // stride 12288 sh; 2 buffers = 49152 B.  Q/K epilogue reuses [0,18432).
    __shared__ unsigned short SM[24576];

    const int tid  = threadIdx.x;
    const int wave = tid >> 6, lane = tid & 63;
    const int quad = lane >> 4, l16 = lane & 15;
    const int wm = wave >> 1, wn = wave & 1;

    // 768 blocks: XCD x owns nfid [x*96, x*96+96) = 4 m-tiles x 24 col-blocks
    const int fid  = blockIdx.y * 24 + blockIdx.x;
    const int nfid = (fid & 7) * 96 + (fid >> 3);
    const int bx = nfid % 24;
    const int m0 = (nfid / 24) * 256;
    const int kk = bx >> 3;
    const int cb = bx & 7;

    // staging: A rows wave*64..+63 (4 chunks of 16), B rows wave*32..+31 (2)
    const int srow = lane >> 2;          // 0..15
    const int sc8  = (lane & 3) * 8;     // 0,8,16,24
    const int row0 = wave * 32 + srow;   // B chunk rows
    const int row1 = row0 + 16;
    const int arow = wave * 64 + srow;   // A chunk base row
    int bn0, bn1;
    if (kk < 2) {
        bn0 = (row0 & 63) * 48 + kk * 16 + cb * 2 + (row0 >> 6);
        bn1 = (row1 & 63) * 48 + kk * 16 + cb * 2 + (row1 >> 6);
    } else {
        bn0 = (cb * 8 + (row0 >> 4)) * 48 + 32 + (row0 & 15);
        bn1 = (cb * 8 + (row1 >> 4)) * 48 + 32 + (row1 & 15);
    }

    floatx4 acc[8][4];
#pragma unroll
    for (int i = 0; i < 8; i++)
#pragma unroll
        for (int j = 0; j < 4; j++) acc[i][j] = (floatx4){0.f, 0.f, 0.f, 0.f};

#define QKV_STAGE(BUF, K0)                                                        \
    do {                                                                          \
        GLD16(&x[(m0 + arow) * 1024 + (K0) + sc8],                                \
              &SM[(BUF) * 12288 + (wave * 64) * 32]);                             \
        GLD16(&x[(m0 + arow + 16) * 1024 + (K0) + sc8],                           \
              &SM[(BUF) * 12288 + (wave * 64 + 16) * 32]);                        \
        GLD16(&x[(m0 + arow + 32) * 1024 + (K0) + sc8],                           \
              &SM[(BUF) * 12288 + (wave * 64 + 32) * 32]);                        \
        GLD16(&x[(m0 + arow + 48) * 1024 + (K0) + sc8],                           \
              &SM[(BUF) * 12288 + (wave * 64 + 48) * 32]);                        \
        GLD16(&wq[bn0 * 1024 + (K0) + sc8],                                       \
              &SM[(BUF) * 12288 + 8192 + (wave * 32) * 32]);                      \
        GLD16(&wq[bn1 * 1024 + (K0) + sc8],                                       \
              &SM[(BUF) * 12288 + 8192 + (wave * 32 + 16) * 32]);                 \
    } while (0)

    QKV_STAGE(0, 0);
    int buf = 0;
    for (int k0 = 0; k0 < 1024; k0 += 32) {
        __syncthreads();
        if (k0 + 32 < 1024) QKV_STAGE(buf ^ 1, k0 + 32);

        const unsigned short* Ab = &SM[buf * 12288];
        const unsigned short* Bb = Ab + 8192;
        short8 af[8], bfv[4];
#pragma unroll
        for (int mi = 0; mi < 8; mi++)
            af[mi] = *(const short8*)&Ab[(wm * 128 + mi * 16 + l16) * 32 + quad * 8];
#pragma unroll
        for (int ni = 0; ni < 4; ni++)
            bfv[ni] = *(const short8*)&Bb[(wn * 64 + ni * 16 + l16) * 32 + quad * 8];
#pragma unroll
        for (int mi = 0; mi < 8; mi++)
#pragma unroll
            for (int ni = 0; ni < 4; ni++)
                acc[mi][ni] = mfma16(af[mi], bfv[ni], acc[mi][ni]);
        buf ^= 1;
    }
    __syncthreads();

    if (kk == 2) {
        // V epilogue: [bh][d][t], packed ushort4 along t
#pragma unroll
        for (int ni = 0; ni < 4; ni++) {
            const int d = cb * 8 + wn * 4 + ni;
#pragma unroll
            for (int mi = 0; mi < 8; mi++) {
                const int m  = m0 + wm * 128 + mi * 16 + quad * 4;
                const int b  = m >> 11;
                const int tt = m & 2047;
                ushort4 pk;
                pk.x = f2bf_bits(acc[mi][ni][0]);
                pk.y = f2bf_bits(acc[mi][ni][1]);
                pk.z = f2bf_bits(acc[mi][ni][2]);
                pk.w = f2bf_bits(acc[mi][ni][3]);
                *(ushort4*)&vb[((b * 16 + l16) * 64 + d) * 2048 + tt] = pk;
            }
        }
    } else {
        // Q/K epilogue: LDS transpose [256][72] -> [bh][t][d], one h-slab/pass
        const float scale = (kk == 0) ? 0.045084220027780106f : 1.0f;  // log2(e)/32
        unsigned short* dst = (kk == 0) ? qb : kb;
        const int b = m0 >> 11, tt0 = m0 & 2047;   // block lies in one batch
#pragma unroll
        for (int s = 0; s < 2; s++) {
            if (wn == s) {  // waves s and s+2 own this h-slab (wm = 0,1)
#pragma unroll
                for (int ni = 0; ni < 4; ni++) {
                    const int d = ni * 16 + l16;
#pragma unroll
                    for (int mi = 0; mi < 8; mi++) {
                        const int tl = wm * 128 + mi * 16 + quad * 4;
#pragma unroll
                        for (int r = 0; r < 4; r++)
                            SM[(tl + r) * 72 + d] = f2bf_bits(acc[mi][ni][r] * scale);
                    }
                }
            }
            __syncthreads();
            // coalesced read-back: 256 rows x 64 cols
#pragma unroll
            for (int u = 0; u < 8; u++) {
                const int w  = tid + u * 256;     // 0..2047
                const int tl = w >> 3;
                const int ch = (w & 7) * 8;
                *(uint4*)&dst[((b * 16 + cb * 2 + s) * 2048 + tt0 + tl) * 64 + ch] =
                    *(const uint4*)&SM[tl * 72 + ch];
            }
            __syncthreads();
        }
    }
#undef QKV_STAGE
}

// ---------------------------------------------------------------------------
// Kernel 2: flash attention — round-8 version UNCHANGED (best measured:
// 82.5 µs; cross-tile pipeline, 4-buffer LDS, in-register softmax).
// ---------------------------------------------------------------------------
__global__ __launch_bounds__(256, 2) void k_attn(
    const unsigned short* __restrict__ qt,  // [64][2048][64]  (bh, t, d)
    const unsigned short* __restrict__ kt,  // [64][2048][64]
    const unsigned short* __restrict__ vg,  // [64][64][2048]  (bh, d, t)
    __hip_bfloat16* __restrict__ og)        // [4][2048][1024]
{
    __shared__ unsigned short Ks[4 * 4608];  // [buf][key][d]   36864 B
    __shared__ unsigned short Vt[4 * 4608];  // [buf][d][key]   36864 B

    const int tid  = threadIdx.x;
    const int wave = tid >> 6, lane = tid & 63;
    const int l31  = lane & 31, hi = lane >> 5;
    const int blk = blockIdx.x;
    const int bh  = (blk & 7) | ((blk >> 6) << 3);  // XCD-affine
    const int q0  = ((blk >> 3) & 7) * 256;
    const int qr  = q0 + wave * 64;

    short8 qf[2][4];
#pragma unroll
    for (int qb2 = 0; qb2 < 2; qb2++)
#pragma unroll
        for (int ks = 0; ks < 4; ks++)
            qf[qb2][ks] = *(const short8*)
                &qt[(bh * 2048 + qr + qb2 * 32 + l31) * 64 + ks * 16 + hi * 8];

    float lsum[2] = {0.f, 0.f};
    floatx16 o[2][2];
#pragma unroll
    for (int qb2 = 0; qb2 < 2; qb2++)
#pragma unroll
        for (int db = 0; db < 2; db++)
#pragma unroll
            for (int r = 0; r < 16; r++) o[qb2][db][r] = 0.f;

    const int sr = tid >> 2, sc = (tid & 3) * 16;
    const unsigned short* kR = &kt[(bh * 2048 + sr) * 64 + sc];  // tile t: +t*4096
    const unsigned short* vR = &vg[(bh * 64 + sr) * 2048 + sc];  // tile t: +t*64

    uint4 rka, rkb, rva, rvb;
#define LOADT(T)                                                   \
    do {                                                           \
        rka = *(const uint4*)&kR[(T) * 4096];                      \
        rkb = *(const uint4*)&kR[(T) * 4096 + 8];                  \
        rva = *(const uint4*)&vR[(T) * 64];                        \
        rvb = *(const uint4*)&vR[(T) * 64 + 8];                    \
    } while (0)
#define WRITET(B)                                                  \
    do {                                                           \
        *(uint4*)&Ks[(B) * 4608 + sr * 72 + sc]     = rka;         \
        *(uint4*)&Ks[(B) * 4608 + sr * 72 + sc + 8] = rkb;         \
        *(uint4*)&Vt[(B) * 4608 + sr * 72 + sc]     = rva;         \
        *(uint4*)&Vt[(B) * 4608 + sr * 72 + sc + 8] = rvb;         \
    } while (0)

#define SOFTMAX(ST, PAF)                                                        \
    do {                                                                        \
        _Pragma("unroll")                                                       \
        for (int qb2 = 0; qb2 < 2; qb2++) {                                     \
            float p[16];                                                        \
            _Pragma("unroll")                                                   \
            for (int r = 0; r < 16; r++) p[r] = fast_exp2((ST)[qb2][r]);        \
            lsum[qb2] += (((p[0] + p[1]) + (p[2] + p[3])) +                     \
                          ((p[4] + p[5]) + (p[6] + p[7]))) +                    \
                         (((p[8] + p[9]) + (p[10] + p[11])) +                   \
                          ((p[12] + p[13]) + (p[14] + p[15])));                 \
            _Pragma("unroll")                                                   \
            for (int hf = 0; hf < 2; hf++) {                                    \
                const int r0 = hf * 8;                                          \
                unsigned c01 = cvt_pk_bf16(p[r0 + 0], p[r0 + 1]);               \
                unsigned c23 = cvt_pk_bf16(p[r0 + 2], p[r0 + 3]);               \
                unsigned c45 = cvt_pk_bf16(p[r0 + 4], p[r0 + 5]);               \
                unsigned c67 = cvt_pk_bf16(p[r0 + 6], p[r0 + 7]);               \
                plane32_swap(c01, c45);                                         \
                plane32_swap(c23, c67);                                         \
                uint4 t4 = {c01, c23, c45, c67};                                \
                (PAF)[qb2][hf] = *reinterpret_cast<short8*>(&t4);               \
            }                                                                   \
        }                                                                       \
    } while (0)

#define PV(PAF, BO, KB2)                                                        \
    do {                                                                        \
        short8 vf[2][2];                                                        \
        _Pragma("unroll")                                                       \
        for (int db = 0; db < 2; db++)                                          \
            _Pragma("unroll")                                                   \
            for (int hf = 0; hf < 2; hf++)                                      \
                vf[db][hf] = *(const short8*)&Vt[(BO) + (db * 32 + l31) * 72 +  \
                                                 (KB2) * 32 + hf * 16 + hi * 8];\
        __builtin_amdgcn_s_setprio(1);                                          \
        _Pragma("unroll")                                                       \
        for (int qb2 = 0; qb2 < 2; qb2++)                                       \
            _Pragma("unroll")                                                   \
            for (int db = 0; db < 2; db++)                                      \
                _Pragma("unroll")                                               \
                for (int hf = 0; hf < 2; hf++)                                  \
                    o[qb2][db] = mfma32((PAF)[qb2][hf], vf[db][hf], o[qb2][db]);\
        __builtin_amdgcn_s_setprio(0);                                          \
    } while (0)

#define QK(ST, BO, KB2)                                                         \
    do {                                                                        \
        short8 kf[4];                                                           \
        _Pragma("unroll")                                                       \
        for (int ks = 0; ks < 4; ks++)                                          \
            kf[ks] = *(const short8*)&Ks[(BO) + ((KB2) * 32 + l31) * 72 +       \
                                         ks * 16 + hi * 8];                     \
        _Pragma("unroll")                                                       \
        for (int qb2 = 0; qb2 < 2; qb2++)                                       \
            _Pragma("unroll")                                                   \
            for (int r = 0; r < 16; r++) (ST)[qb2][r] = 0.f;                    \
        __builtin_amdgcn_s_setprio(1);                                          \
        _Pragma("unroll")                                                       \
        for (int ks = 0; ks < 4; ks++)                                          \
            _Pragma("unroll")                                                   \
            for (int qb2 = 0; qb2 < 2; qb2++)                                   \
                (ST)[qb2] = mfma32(kf[ks], qf[qb2][ks], (ST)[qb2]);             \
        __builtin_amdgcn_s_setprio(0);                                          \
    } while (0)

    LOADT(0);
    WRITET(0);
    LOADT(1);
    WRITET(1);
    LOADT(2);
    asm volatile("s_waitcnt lgkmcnt(0)" ::: "memory");
    __builtin_amdgcn_s_barrier();
    __builtin_amdgcn_sched_barrier(0);

    floatx16 stP[2];
    QK(stP, 0, 0);

    for (int j = 0; j < 32; ++j) {
        const int bj  = (j & 3) * 4608;
        const int bj1 = ((j + 1) & 3) * 4608;
        if (j <= 29) WRITET((j + 2) & 3);
        if (j <= 28) LOADT(j + 3);

        floatx16 stN[2];
        QK(stN, bj, 1);
        short8 pafP[2][2];
        SOFTMAX(stP, pafP);
        PV(pafP, bj, 0);

        if (j <= 30) QK(stP, bj1, 0);
        short8 pafN[2][2];
        SOFTMAX(stN, pafN);
        PV(pafN, bj, 1);

        asm volatile("s_waitcnt lgkmcnt(0)" ::: "memory");
        __builtin_amdgcn_s_barrier();
        __builtin_amdgcn_sched_barrier(0);
    }
#undef QK
#undef PV
#undef SOFTMAX
#undef WRITET
#undef LOADT

    lsum[0] += __shfl_xor(lsum[0], 32);
    lsum[1] += __shfl_xor(lsum[1], 32);

    const int b = bh >> 4, h = bh & 15;
#pragma unroll
    for (int qb2 = 0; qb2 < 2; qb2++) {
#pragma unroll
        for (int r = 0; r < 16; r++) {
            const int qrl = (r & 3) + 8 * (r >> 2) + 4 * hi;
            const float inv = 1.0f / __shfl(lsum[qb2], qrl);
            const int t = qr + qb2 * 32 + qrl;
#pragma unroll
            for (int db = 0; db < 2; db++)
                og[(b * 2048 + t) * 1024 + h * 64 + db * 32 + l31] =
                    __float2bfloat16(o[qb2][db][r] * inv);
        }
    }
}

// ---------------------------------------------------------------------------
// Kernel 3: output projection — same 256x128 / wave 128x64 redesign.
// ---------------------------------------------------------------------------
__global__ __launch_bounds__(256, 2) void k_out(
    const unsigned short* __restrict__ a,    // [8192][1024] bf16
    const unsigned short* __restrict__ wq,   // [1024][1024] bf16
    const float* __restrict__ bias,
    float* __restrict__ out)                 // [8192][1024] fp32
{
    __shared__ unsigned short SM[24576];

    const int tid  = threadIdx.x;
    const int wave = tid >> 6, lane = tid & 63;
    const int quad = lane >> 4, l16 = lane & 15;
    const int wm = wave >> 1, wn = wave & 1;

    // 256 blocks: XCD x owns nfid [x*32, x*32+32) = 4 m-tiles x 8 col-blocks
    const int fid  = blockIdx.y * 8 + blockIdx.x;
    const int nfid = (fid & 7) * 32 + (fid >> 3);
    const int n0 = (nfid & 7) * 128;
    const int m0 = (nfid >> 3) * 256;

    const int srow = lane >> 2;
    const int sc8  = (lane & 3) * 8;
    const int row0 = wave * 32 + srow;
    const int row1 = row0 + 16;
    const int arow = wave * 64 + srow;

    floatx4 acc[8][4];
#pragma unroll
    for (int i = 0; i < 8; i++)
#pragma unroll
        for (int j = 0; j < 4; j++) acc[i][j] = (floatx4){0.f, 0.f, 0.f, 0.f};

#define OUT_STAGE(BUF, K0)                                                        \
    do {                                                                          \
        GLD16(&a[(m0 + arow) * 1024 + (K0) + sc8],                                \
              &SM[(BUF) * 12288 + (wave * 64) * 32]);                             \
        GLD16(&a[(m0 + arow + 16) * 1024 + (K0) + sc8],                           \
              &SM[(BUF) * 12288 + (wave * 64 + 16) * 32]);                        \
        GLD16(&a[(m0 + arow + 32) * 1024 + (K0) + sc8],                           \
              &SM[(BUF) * 12288 + (wave * 64 + 32) * 32]);                        \
        GLD16(&a[(m0 + arow + 48) * 1024 + (K0) + sc8],                           \
              &SM[(BUF) * 12288 + (wave * 64 + 48) * 32]);                        \
        GLD16(&wq[(n0 + row0) * 1024 + (K0) + sc8],                               \
              &SM[(BUF) * 12288 + 8192 + (wave * 32) * 32]);                      \
        GLD16(&wq[(n0 + row1) * 1024 + (K0) + sc8],                               \
              &SM[(BUF) * 12288 + 8192 + (wave * 32 + 16) * 32]);                 \
    } while (0)

    OUT_STAGE(0, 0);
    int buf = 0;
    for (int k0 = 0; k0 < 1024; k0 += 32) {
        __syncthreads();
        if (k0 + 32 < 1024) OUT_STAGE(buf ^ 1, k0 + 32);

        const unsigned short* Ab = &SM[buf * 12288];
        const unsigned short* Bb = Ab + 8192;
        short8 af[8], bfv[4];
#pragma unroll
        for (int mi = 0; mi < 8; mi++)
            af[mi] = *(const short8*)&Ab[(wm * 128 + mi * 16 + l16) * 32 + quad * 8];
#pragma unroll
        for (int ni = 0; ni < 4; ni++)
            bfv[ni] = *(const short8*)&Bb[(wn * 64 + ni * 16 + l16) * 32 + quad * 8];
#pragma unroll
        for (int mi = 0; mi < 8; mi++)
#pragma unroll
            for (int ni = 0; ni < 4; ni++)
                acc[mi][ni] = mfma16(af[mi], bfv[ni], acc[mi][ni]);
        buf ^= 1;
    }
#undef OUT_STAGE

#pragma unroll
    for (int ni = 0; ni < 4; ni++) {
        const int col = n0 + wn * 64 + ni * 16 + l16;
        const float bv = bias[col];
#pragma unroll
        for (int mi = 0; mi < 8; mi++) {
            const int mbase = m0 + wm * 128 + mi * 16 + quad * 4;
#pragma unroll
            for (int r = 0; r < 4; r++)
                out[(mbase + r) * 1024 + col] = acc[mi][ni][r] + bv;
        }
    }
}

// ---------------------------------------------------------------------------
extern "C" void kernel_launch(void* const* d_in, const int* in_sizes, int n_in,
                              void* d_out, int out_size, void* d_ws, size_t ws_size,
                              hipStream_t stream) {
    const float* x    = (const float*)d_in[0];
    const float* wqkv = (const float*)d_in[1];
    const float* wout = (const float*)d_in[2];
    const float* bout = (const float*)d_in[3];
    float* out = (float*)d_out;

    unsigned short* ws = (unsigned short*)d_ws;
    unsigned short* xb    = ws;                  // x bf16
    unsigned short* wqkvb = xb + 8388608;
    unsigned short* woutb = wqkvb + 3145728;
    unsigned short* qb    = woutb + 1048576;     // q [bh][t][d]
    unsigned short* kb    = qb + 8388608;        // k [bh][t][d]
    unsigned short* vb    = kb + 8388608;        // v [bh][d][t]
    unsigned short* ob    = vb + 8388608;        // attn out

    k_cvt<<<2048, 256, 0, stream>>>(x,    xb,    8388608 / 4);
    k_cvt<<<1024, 256, 0, stream>>>(wqkv, wqkvb, 3145728 / 4);
    k_cvt<<<512,  256, 0, stream>>>(wout, woutb, 1048576 / 4);

    k_qkv<<<dim3(24, 32), 256, 0, stream>>>(xb, wqkvb, qb, kb, vb);
    k_attn<<<512, 256, 0, stream>>>(qb, kb, vb, (__hip_bfloat16*)ob);
    k_out<<<dim3(8, 32), 256, 0, stream>>>(ob, woutb, bout, out);
}

// Round 10
// 282.127 us; speedup vs baseline: 1.0362x; 1.0362x over previous
//
#include <hip/hip_runtime.h>
#include <hip/hip_bf16.h>

// Problem: B=4, T=2048, DIM=1024, H=16, DH=64.  fp32 in/out, bf16 MFMA inside.
// qkv col o = d*48 + kk*16 + h (d outermost, h innermost).

typedef __attribute__((ext_vector_type(8))) short short8;
typedef __attribute__((ext_vector_type(4))) float floatx4;
typedef __attribute__((ext_vector_type(16))) float floatx16;

static __device__ __forceinline__ floatx4 mfma16(short8 a, short8 b, floatx4 c) {
    return __builtin_amdgcn_mfma_f32_16x16x32_bf16(a, b, c, 0, 0, 0);
}
static __device__ __forceinline__ floatx16 mfma32(short8 a, short8 b, floatx16 c) {
    return __builtin_amdgcn_mfma_f32_32x32x16_bf16(a, b, c, 0, 0, 0);
}

static __device__ __forceinline__ unsigned short f2bf_bits(float f) {
    __hip_bfloat16 h = __float2bfloat16(f);
    return *reinterpret_cast<unsigned short*>(&h);
}

static __device__ __forceinline__ float fast_exp2(float x) {
#if __has_builtin(__builtin_amdgcn_exp2f)
    return __builtin_amdgcn_exp2f(x);
#else
    return exp2f(x);
#endif
}

// pack two f32 -> one u32 of 2 bf16 (lo in [15:0], hi in [31:16])
static __device__ __forceinline__ unsigned cvt_pk_bf16(float lo, float hi) {
    unsigned r;
    asm("v_cvt_pk_bf16_f32 %0, %1, %2" : "=v"(r) : "v"(lo), "v"(hi));
    return r;
}

// m214-verified idiom: swap(pk(p0,p1), pk(p4,p5)) -> both outputs usable.
static __device__ __forceinline__ void plane32_swap(unsigned& x, unsigned& y) {
#if __has_builtin(__builtin_amdgcn_permlane32_swap)
    typedef unsigned int uintx2 __attribute__((ext_vector_type(2)));
    uintx2 r = __builtin_amdgcn_permlane32_swap(x, y, false, false);
    x = r[0];
    y = r[1];
#else
    asm volatile("v_permlane32_swap_b32 %0, %1" : "+v"(x), "+v"(y));
#endif
}

// async global->LDS, 16 B per lane; LDS dest = wave-uniform base + lane*16
#define GLD16(gptr, ldsptr)                                                  \
    __builtin_amdgcn_global_load_lds(                                        \
        (const __attribute__((address_space(1))) void*)(gptr),               \
        (__attribute__((address_space(3))) void*)(ldsptr), 16, 0, 0)

// ---------------------------------------------------------------------------
// Kernel 0: fp32 -> bf16 conversion (three launches — verified).
// ---------------------------------------------------------------------------
__global__ __launch_bounds__(256) void k_cvt(
    const float* __restrict__ src, unsigned short* __restrict__ dst, int n4)
{
    typedef __attribute__((ext_vector_type(4))) unsigned short ushort4v;
    for (int i = blockIdx.x * blockDim.x + threadIdx.x; i < n4;
         i += gridDim.x * blockDim.x) {
        const float4 v = ((const float4*)src)[i];
        ushort4v o;
        o.x = f2bf_bits(v.x);
        o.y = f2bf_bits(v.y);
        o.z = f2bf_bits(v.z);
        o.w = f2bf_bits(v.w);
        ((ushort4v*)dst)[i] = o;
    }
}

// ---------------------------------------------------------------------------
// Kernel 1: QKV projection — r2-verified 128² 2-phase dbuf structure (tile
// space at this structure is measured: 128² optimal).  ONLY change vs r2:
// __launch_bounds__(256,4) squeezes VGPR 132->128 to unlock 4 waves/SIMD
// (latency-bound kernel; residency was VGPR-capped at 3 waves/SIMD).
// ---------------------------------------------------------------------------
__global__ __launch_bounds__(256, 4) void k_qkv(
    const unsigned short* __restrict__ x,   // [8192][1024] bf16
    const unsigned short* __restrict__ wq,  // [3072][1024] bf16
    unsigned short* __restrict__ qb,        // [64 bh][2048 t][64 d]
    unsigned short* __restrict__ kb,        // [64 bh][2048 t][64 d]
    unsigned short* __restrict__ vb)        // [64 bh][64 d][2048 t]
{
    __shared__ unsigned short SM[16384];

    const int tid  = threadIdx.x;
    const int wave = tid >> 6, lane = tid & 63;
    const int quad = lane >> 4, l16 = lane & 15;
    const int wm = wave >> 1, wn = wave & 1;

    const int fid  = blockIdx.y * 24 + blockIdx.x;
    const int nfid = (fid & 7) * 192 + (fid >> 3);
    const int bx = nfid % 24;
    const int m0 = (nfid / 24) * 128;
    const int kk = bx >> 3;
    const int cb = bx & 7;

    const int srow = lane >> 2;          // 0..15
    const int sc8  = (lane & 3) * 8;     // 0,8,16,24
    const int row0 = wave * 32 + srow;
    const int row1 = row0 + 16;
    int bn0, bn1;
    if (kk < 2) {
        bn0 = (row0 & 63) * 48 + kk * 16 + cb * 2 + (row0 >> 6);
        bn1 = (row1 & 63) * 48 + kk * 16 + cb * 2 + (row1 >> 6);
    } else {
        bn0 = (cb * 8 + (row0 >> 4)) * 48 + 32 + (row0 & 15);
        bn1 = (cb * 8 + (row1 >> 4)) * 48 + 32 + (row1 & 15);
    }

    floatx4 acc[4][4];
#pragma unroll
    for (int i = 0; i < 4; i++)
#pragma unroll
        for (int j = 0; j < 4; j++) acc[i][j] = (floatx4){0.f, 0.f, 0.f, 0.f};

#define QKV_STAGE(BUF, K0)                                                        \
    do {                                                                          \
        GLD16(&x[(m0 + row0) * 1024 + (K0) + sc8],                                \
              &SM[(BUF) * 8192 + (wave * 32) * 32]);                              \
        GLD16(&x[(m0 + row1) * 1024 + (K0) + sc8],                                \
              &SM[(BUF) * 8192 + (wave * 32 + 16) * 32]);                         \
        GLD16(&wq[bn0 * 1024 + (K0) + sc8],                                       \
              &SM[(BUF) * 8192 + 4096 + (wave * 32) * 32]);                       \
        GLD16(&wq[bn1 * 1024 + (K0) + sc8],                                       \
              &SM[(BUF) * 8192 + 4096 + (wave * 32 + 16) * 32]);                  \
    } while (0)

    QKV_STAGE(0, 0);
    int buf = 0;
    for (int k0 = 0; k0 < 1024; k0 += 32) {
        __syncthreads();
        if (k0 + 32 < 1024) QKV_STAGE(buf ^ 1, k0 + 32);

        const unsigned short* Ab = &SM[buf * 8192];
        const unsigned short* Bb = Ab + 4096;
        short8 af[4], bfv[4];
#pragma unroll
        for (int mi = 0; mi < 4; mi++)
            af[mi] = *(const short8*)&Ab[(wm * 64 + mi * 16 + l16) * 32 + quad * 8];
#pragma unroll
        for (int ni = 0; ni < 4; ni++)
            bfv[ni] = *(const short8*)&Bb[(wn * 64 + ni * 16 + l16) * 32 + quad * 8];
#pragma unroll
        for (int mi = 0; mi < 4; mi++)
#pragma unroll
            for (int ni = 0; ni < 4; ni++)
                acc[mi][ni] = mfma16(af[mi], bfv[ni], acc[mi][ni]);
        buf ^= 1;
    }
    __syncthreads();

    if (kk == 2) {
#pragma unroll
        for (int ni = 0; ni < 4; ni++) {
            const int d = cb * 8 + wn * 4 + ni;
#pragma unroll
            for (int mi = 0; mi < 4; mi++) {
                const int m  = m0 + wm * 64 + mi * 16 + quad * 4;
                const int b  = m >> 11;
                const int tt = m & 2047;
                ushort4 pk;
                pk.x = f2bf_bits(acc[mi][ni][0]);
                pk.y = f2bf_bits(acc[mi][ni][1]);
                pk.z = f2bf_bits(acc[mi][ni][2]);
                pk.w = f2bf_bits(acc[mi][ni][3]);
                *(ushort4*)&vb[((b * 16 + l16) * 64 + d) * 2048 + tt] = pk;
            }
        }
    } else {
        const float scale = (kk == 0) ? 0.045084220027780106f : 1.0f;  // log2(e)/32
        unsigned short* dst = (kk == 0) ? qb : kb;
        const int b = m0 >> 11, tt0 = m0 & 2047;
#pragma unroll
        for (int s = 0; s < 2; s++) {
            if (wn == s) {
#pragma unroll
                for (int ni = 0; ni < 4; ni++) {
                    const int d = ni * 16 + l16;
#pragma unroll
                    for (int mi = 0; mi < 4; mi++) {
                        const int tl = wm * 64 + mi * 16 + quad * 4;
#pragma unroll
                        for (int r = 0; r < 4; r++)
                            SM[(tl + r) * 72 + d] = f2bf_bits(acc[mi][ni][r] * scale);
                    }
                }
            }
            __syncthreads();
#pragma unroll
            for (int u = 0; u < 4; u++) {
                const int w  = tid + u * 256;
                const int tl = w >> 3;
                const int ch = (w & 7) * 8;
                *(uint4*)&dst[((b * 16 + cb * 2 + s) * 2048 + tt0 + tl) * 64 + ch] =
                    *(const uint4*)&SM[tl * 72 + ch];
            }
            __syncthreads();
        }
    }
#undef QKV_STAGE
}

// ---------------------------------------------------------------------------
// Kernel 2: flash attention — round-8 version UNCHANGED (best measured:
// 82.5 µs; cross-tile pipeline, 4-buffer LDS, in-register softmax).
// ---------------------------------------------------------------------------
__global__ __launch_bounds__(256, 2) void k_attn(
    const unsigned short* __restrict__ qt,  // [64][2048][64]  (bh, t, d)
    const unsigned short* __restrict__ kt,  // [64][2048][64]
    const unsigned short* __restrict__ vg,  // [64][64][2048]  (bh, d, t)
    __hip_bfloat16* __restrict__ og)        // [4][2048][1024]
{
    __shared__ unsigned short Ks[4 * 4608];  // [buf][key][d]   36864 B
    __shared__ unsigned short Vt[4 * 4608];  // [buf][d][key]   36864 B

    const int tid  = threadIdx.x;
    const int wave = tid >> 6, lane = tid & 63;
    const int l31  = lane & 31, hi = lane >> 5;
    const int blk = blockIdx.x;
    const int bh  = (blk & 7) | ((blk >> 6) << 3);  // XCD-affine
    const int q0  = ((blk >> 3) & 7) * 256;
    const int qr  = q0 + wave * 64;

    short8 qf[2][4];
#pragma unroll
    for (int qb2 = 0; qb2 < 2; qb2++)
#pragma unroll
        for (int ks = 0; ks < 4; ks++)
            qf[qb2][ks] = *(const short8*)
                &qt[(bh * 2048 + qr + qb2 * 32 + l31) * 64 + ks * 16 + hi * 8];

    float lsum[2] = {0.f, 0.f};
    floatx16 o[2][2];
#pragma unroll
    for (int qb2 = 0; qb2 < 2; qb2++)
#pragma unroll
        for (int db = 0; db < 2; db++)
#pragma unroll
            for (int r = 0; r < 16; r++) o[qb2][db][r] = 0.f;

    const int sr = tid >> 2, sc = (tid & 3) * 16;
    const unsigned short* kR = &kt[(bh * 2048 + sr) * 64 + sc];  // tile t: +t*4096
    const unsigned short* vR = &vg[(bh * 64 + sr) * 2048 + sc];  // tile t: +t*64

    uint4 rka, rkb, rva, rvb;
#define LOADT(T)                                                   \
    do {                                                           \
        rka = *(const uint4*)&kR[(T) * 4096];                      \
        rkb = *(const uint4*)&kR[(T) * 4096 + 8];                  \
        rva = *(const uint4*)&vR[(T) * 64];                        \
        rvb = *(const uint4*)&vR[(T) * 64 + 8];                    \
    } while (0)
#define WRITET(B)                                                  \
    do {                                                           \
        *(uint4*)&Ks[(B) * 4608 + sr * 72 + sc]     = rka;         \
        *(uint4*)&Ks[(B) * 4608 + sr * 72 + sc + 8] = rkb;         \
        *(uint4*)&Vt[(B) * 4608 + sr * 72 + sc]     = rva;         \
        *(uint4*)&Vt[(B) * 4608 + sr * 72 + sc + 8] = rvb;         \
    } while (0)

#define SOFTMAX(ST, PAF)                                                        \
    do {                                                                        \
        _Pragma("unroll")                                                       \
        for (int qb2 = 0; qb2 < 2; qb2++) {                                     \
            float p[16];                                                        \
            _Pragma("unroll")                                                   \
            for (int r = 0; r < 16; r++) p[r] = fast_exp2((ST)[qb2][r]);        \
            lsum[qb2] += (((p[0] + p[1]) + (p[2] + p[3])) +                     \
                          ((p[4] + p[5]) + (p[6] + p[7]))) +                    \
                         (((p[8] + p[9]) + (p[10] + p[11])) +                   \
                          ((p[12] + p[13]) + (p[14] + p[15])));                 \
            _Pragma("unroll")                                                   \
            for (int hf = 0; hf < 2; hf++) {                                    \
                const int r0 = hf * 8;                                          \
                unsigned c01 = cvt_pk_bf16(p[r0 + 0], p[r0 + 1]);               \
                unsigned c23 = cvt_pk_bf16(p[r0 + 2], p[r0 + 3]);               \
                unsigned c45 = cvt_pk_bf16(p[r0 + 4], p[r0 + 5]);               \
                unsigned c67 = cvt_pk_bf16(p[r0 + 6], p[r0 + 7]);               \
                plane32_swap(c01, c45);                                         \
                plane32_swap(c23, c67);                                         \
                uint4 t4 = {c01, c23, c45, c67};                                \
                (PAF)[qb2][hf] = *reinterpret_cast<short8*>(&t4);               \
            }                                                                   \
        }                                                                       \
    } while (0)

#define PV(PAF, BO, KB2)                                                        \
    do {                                                                        \
        short8 vf[2][2];                                                        \
        _Pragma("unroll")                                                       \
        for (int db = 0; db < 2; db++)                                          \
            _Pragma("unroll")                                                   \
            for (int hf = 0; hf < 2; hf++)                                      \
                vf[db][hf] = *(const short8*)&Vt[(BO) + (db * 32 + l31) * 72 +  \
                                                 (KB2) * 32 + hf * 16 + hi * 8];\
        __builtin_amdgcn_s_setprio(1);                                          \
        _Pragma("unroll")                                                       \
        for (int qb2 = 0; qb2 < 2; qb2++)                                       \
            _Pragma("unroll")                                                   \
            for (int db = 0; db < 2; db++)                                      \
                _Pragma("unroll")                                               \
                for (int hf = 0; hf < 2; hf++)                                  \
                    o[qb2][db] = mfma32((PAF)[qb2][hf], vf[db][hf], o[qb2][db]);\
        __builtin_amdgcn_s_setprio(0);                                          \
    } while (0)

#define QK(ST, BO, KB2)                                                         \
    do {                                                                        \
        short8 kf[4];                                                           \
        _Pragma("unroll")                                                       \
        for (int ks = 0; ks < 4; ks++)                                          \
            kf[ks] = *(const short8*)&Ks[(BO) + ((KB2) * 32 + l31) * 72 +       \
                                         ks * 16 + hi * 8];                     \
        _Pragma("unroll")                                                       \
        for (int qb2 = 0; qb2 < 2; qb2++)                                       \
            _Pragma("unroll")                                                   \
            for (int r = 0; r < 16; r++) (ST)[qb2][r] = 0.f;                    \
        __builtin_amdgcn_s_setprio(1);                                          \
        _Pragma("unroll")                                                       \
        for (int ks = 0; ks < 4; ks++)                                          \
            _Pragma("unroll")                                                   \
            for (int qb2 = 0; qb2 < 2; qb2++)                                   \
                (ST)[qb2] = mfma32(kf[ks], qf[qb2][ks], (ST)[qb2]);             \
        __builtin_amdgcn_s_setprio(0);                                          \
    } while (0)

    LOADT(0);
    WRITET(0);
    LOADT(1);
    WRITET(1);
    LOADT(2);
    asm volatile("s_waitcnt lgkmcnt(0)" ::: "memory");
    __builtin_amdgcn_s_barrier();
    __builtin_amdgcn_sched_barrier(0);

    floatx16 stP[2];
    QK(stP, 0, 0);

    for (int j = 0; j < 32; ++j) {
        const int bj  = (j & 3) * 4608;
        const int bj1 = ((j + 1) & 3) * 4608;
        if (j <= 29) WRITET((j + 2) & 3);
        if (j <= 28) LOADT(j + 3);

        floatx16 stN[2];
        QK(stN, bj, 1);
        short8 pafP[2][2];
        SOFTMAX(stP, pafP);
        PV(pafP, bj, 0);

        if (j <= 30) QK(stP, bj1, 0);
        short8 pafN[2][2];
        SOFTMAX(stN, pafN);
        PV(pafN, bj, 1);

        asm volatile("s_waitcnt lgkmcnt(0)" ::: "memory");
        __builtin_amdgcn_s_barrier();
        __builtin_amdgcn_sched_barrier(0);
    }
#undef QK
#undef PV
#undef SOFTMAX
#undef WRITET
#undef LOADT

    lsum[0] += __shfl_xor(lsum[0], 32);
    lsum[1] += __shfl_xor(lsum[1], 32);

    const int b = bh >> 4, h = bh & 15;
#pragma unroll
    for (int qb2 = 0; qb2 < 2; qb2++) {
#pragma unroll
        for (int r = 0; r < 16; r++) {
            const int qrl = (r & 3) + 8 * (r >> 2) + 4 * hi;
            const float inv = 1.0f / __shfl(lsum[qb2], qrl);
            const int t = qr + qb2 * 32 + qrl;
#pragma unroll
            for (int db = 0; db < 2; db++)
                og[(b * 2048 + t) * 1024 + h * 64 + db * 32 + l31] =
                    __float2bfloat16(o[qb2][db][r] * inv);
        }
    }
}

// ---------------------------------------------------------------------------
// Kernel 3: output projection — r2-verified 128² structure; only change is
// __launch_bounds__(256,4) (same occupancy rationale as k_qkv).
// ---------------------------------------------------------------------------
__global__ __launch_bounds__(256, 4) void k_out(
    const unsigned short* __restrict__ a,    // [8192][1024] bf16
    const unsigned short* __restrict__ wq,   // [1024][1024] bf16
    const float* __restrict__ bias,
    float* __restrict__ out)                 // [8192][1024] fp32
{
    __shared__ unsigned short SM[16384];

    const int tid  = threadIdx.x;
    const int wave = tid >> 6, lane = tid & 63;
    const int quad = lane >> 4, l16 = lane & 15;
    const int wm = wave >> 1, wn = wave & 1;

    const int fid  = blockIdx.y * 8 + blockIdx.x;
    const int nfid = (fid & 7) * 64 + (fid >> 3);
    const int n0 = (nfid & 7) * 128;
    const int m0 = (nfid >> 3) * 128;

    const int srow = lane >> 2;
    const int sc8  = (lane & 3) * 8;
    const int row0 = wave * 32 + srow;
    const int row1 = row0 + 16;

    floatx4 acc[4][4];
#pragma unroll
    for (int i = 0; i < 4; i++)
#pragma unroll
        for (int j = 0; j < 4; j++) acc[i][j] = (floatx4){0.f, 0.f, 0.f, 0.f};

#define OUT_STAGE(BUF, K0)                                                        \
    do {                                                                          \
        GLD16(&a[(m0 + row0) * 1024 + (K0) + sc8],                                \
              &SM[(BUF) * 8192 + (wave * 32) * 32]);                              \
        GLD16(&a[(m0 + row1) * 1024 + (K0) + sc8],                                \
              &SM[(BUF) * 8192 + (wave * 32 + 16) * 32]);                         \
        GLD16(&wq[(n0 + row0) * 1024 + (K0) + sc8],                               \
              &SM[(BUF) * 8192 + 4096 + (wave * 32) * 32]);                       \
        GLD16(&wq[(n0 + row1) * 1024 + (K0) + sc8],                               \
              &SM[(BUF) * 8192 + 4096 + (wave * 32 + 16) * 32]);                  \
    } while (0)

    OUT_STAGE(0, 0);
    int buf = 0;
    for (int k0 = 0; k0 < 1024; k0 += 32) {
        __syncthreads();
        if (k0 + 32 < 1024) OUT_STAGE(buf ^ 1, k0 + 32);

        const unsigned short* Ab = &SM[buf * 8192];
        const unsigned short* Bb = Ab + 4096;
        short8 af[4], bfv[4];
#pragma unroll
        for (int mi = 0; mi < 4; mi++)
            af[mi] = *(const short8*)&Ab[(wm * 64 + mi * 16 + l16) * 32 + quad * 8];
#pragma unroll
        for (int ni = 0; ni < 4; ni++)
            bfv[ni] = *(const short8*)&Bb[(wn * 64 + ni * 16 + l16) * 32 + quad * 8];
#pragma unroll
        for (int mi = 0; mi < 4; mi++)
#pragma unroll
            for (int ni = 0; ni < 4; ni++)
                acc[mi][ni] = mfma16(af[mi], bfv[ni], acc[mi][ni]);
        buf ^= 1;
    }
#undef OUT_STAGE

#pragma unroll
    for (int ni = 0; ni < 4; ni++) {
        const int col = n0 + wn * 64 + ni * 16 + l16;
        const float bv = bias[col];
#pragma unroll
        for (int mi = 0; mi < 4; mi++) {
            const int mbase = m0 + wm * 64 + mi * 16 + quad * 4;
#pragma unroll
            for (int r = 0; r < 4; r++)
                out[(mbase + r) * 1024 + col] = acc[mi][ni][r] + bv;
        }
    }
}

// ---------------------------------------------------------------------------
extern "C" void kernel_launch(void* const* d_in, const int* in_sizes, int n_in,
                              void* d_out, int out_size, void* d_ws, size_t ws_size,
                              hipStream_t stream) {
    const float* x    = (const float*)d_in[0];
    const float* wqkv = (const float*)d_in[1];
    const float* wout = (const float*)d_in[2];
    const float* bout = (const float*)d_in[3];
    float* out = (float*)d_out;

    unsigned short* ws = (unsigned short*)d_ws;
    unsigned short* xb    = ws;                  // x bf16
    unsigned short* wqkvb = xb + 8388608;
    unsigned short* woutb = wqkvb + 3145728;
    unsigned short* qb    = woutb + 1048576;     // q [bh][t][d]
    unsigned short* kb    = qb + 8388608;        // k [bh][t][d]
    unsigned short* vb    = kb + 8388608;        // v [bh][d][t]
    unsigned short* ob    = vb + 8388608;        // attn out

    k_cvt<<<2048, 256, 0, stream>>>(x,    xb,    8388608 / 4);
    k_cvt<<<1024, 256, 0, stream>>>(wqkv, wqkvb, 3145728 / 4);
    k_cvt<<<512,  256, 0, stream>>>(wout, woutb, 1048576 / 4);

    k_qkv<<<dim3(24, 64), 256, 0, stream>>>(xb, wqkvb, qb, kb, vb);
    k_attn<<<512, 256, 0, stream>>>(qb, kb, vb, (__hip_bfloat16*)ob);
    k_out<<<dim3(8, 64), 256, 0, stream>>>(ob, woutb, bout, out);
}

// Round 11
// 266.863 us; speedup vs baseline: 1.0955x; 1.0572x over previous
//
#include <hip/hip_runtime.h>
#include <hip/hip_bf16.h>

// Problem: B=4, T=2048, DIM=1024, H=16, DH=64.  fp32 in/out, bf16 MFMA inside.
// qkv col o = d*48 + kk*16 + h (d outermost, h innermost).
//
// This is the verified-best configuration (round 8, 254.0 µs):
//  * k_cvt x3 (scalar->bf16, vectorized)
//  * k_qkv / k_out: 128² 2-phase dbuf + XCD-chunked swizzle, natural VGPR
//    (132).  Measured failures on this structure: 256-tile (VGPR spill),
//    launch-bounds squeeze (alloc granule -> 64 VGPR + scratch), counted
//    vmcnt 3-buf (order-pinning).  128²/2-phase is the structure optimum.
//  * k_attn: cross-tile software pipeline (82.5 µs best of 5 schedule
//    variants), 4-buffer LDS, in-register softmax via cvt_pk+permlane32.

typedef __attribute__((ext_vector_type(8))) short short8;
typedef __attribute__((ext_vector_type(4))) float floatx4;
typedef __attribute__((ext_vector_type(16))) float floatx16;

static __device__ __forceinline__ floatx4 mfma16(short8 a, short8 b, floatx4 c) {
    return __builtin_amdgcn_mfma_f32_16x16x32_bf16(a, b, c, 0, 0, 0);
}
static __device__ __forceinline__ floatx16 mfma32(short8 a, short8 b, floatx16 c) {
    return __builtin_amdgcn_mfma_f32_32x32x16_bf16(a, b, c, 0, 0, 0);
}

static __device__ __forceinline__ unsigned short f2bf_bits(float f) {
    __hip_bfloat16 h = __float2bfloat16(f);
    return *reinterpret_cast<unsigned short*>(&h);
}

static __device__ __forceinline__ float fast_exp2(float x) {
#if __has_builtin(__builtin_amdgcn_exp2f)
    return __builtin_amdgcn_exp2f(x);
#else
    return exp2f(x);
#endif
}

// pack two f32 -> one u32 of 2 bf16 (lo in [15:0], hi in [31:16])
static __device__ __forceinline__ unsigned cvt_pk_bf16(float lo, float hi) {
    unsigned r;
    asm("v_cvt_pk_bf16_f32 %0, %1, %2" : "=v"(r) : "v"(lo), "v"(hi));
    return r;
}

// m214-verified idiom: swap(pk(p0,p1), pk(p4,p5)) -> both outputs usable.
static __device__ __forceinline__ void plane32_swap(unsigned& x, unsigned& y) {
#if __has_builtin(__builtin_amdgcn_permlane32_swap)
    typedef unsigned int uintx2 __attribute__((ext_vector_type(2)));
    uintx2 r = __builtin_amdgcn_permlane32_swap(x, y, false, false);
    x = r[0];
    y = r[1];
#else
    asm volatile("v_permlane32_swap_b32 %0, %1" : "+v"(x), "+v"(y));
#endif
}

// async global->LDS, 16 B per lane; LDS dest = wave-uniform base + lane*16
#define GLD16(gptr, ldsptr)                                                  \
    __builtin_amdgcn_global_load_lds(                                        \
        (const __attribute__((address_space(1))) void*)(gptr),               \
        (__attribute__((address_space(3))) void*)(ldsptr), 16, 0, 0)

// ---------------------------------------------------------------------------
// Kernel 0: fp32 -> bf16 conversion (three launches — verified).
// ---------------------------------------------------------------------------
__global__ __launch_bounds__(256) void k_cvt(
    const float* __restrict__ src, unsigned short* __restrict__ dst, int n4)
{
    typedef __attribute__((ext_vector_type(4))) unsigned short ushort4v;
    for (int i = blockIdx.x * blockDim.x + threadIdx.x; i < n4;
         i += gridDim.x * blockDim.x) {
        const float4 v = ((const float4*)src)[i];
        ushort4v o;
        o.x = f2bf_bits(v.x);
        o.y = f2bf_bits(v.y);
        o.z = f2bf_bits(v.z);
        o.w = f2bf_bits(v.w);
        ((ushort4v*)dst)[i] = o;
    }
}

// ---------------------------------------------------------------------------
// Kernel 1: QKV projection — r2-verified 128² 2-phase dbuf + XCD swizzle,
// natural register allocation (132 VGPR, 3 waves/SIMD).
// ---------------------------------------------------------------------------
__global__ __launch_bounds__(256) void k_qkv(
    const unsigned short* __restrict__ x,   // [8192][1024] bf16
    const unsigned short* __restrict__ wq,  // [3072][1024] bf16
    unsigned short* __restrict__ qb,        // [64 bh][2048 t][64 d]
    unsigned short* __restrict__ kb,        // [64 bh][2048 t][64 d]
    unsigned short* __restrict__ vb)        // [64 bh][64 d][2048 t]
{
    __shared__ unsigned short SM[16384];

    const int tid  = threadIdx.x;
    const int wave = tid >> 6, lane = tid & 63;
    const int quad = lane >> 4, l16 = lane & 15;
    const int wm = wave >> 1, wn = wave & 1;

    const int fid  = blockIdx.y * 24 + blockIdx.x;
    const int nfid = (fid & 7) * 192 + (fid >> 3);
    const int bx = nfid % 24;
    const int m0 = (nfid / 24) * 128;
    const int kk = bx >> 3;
    const int cb = bx & 7;

    const int srow = lane >> 2;          // 0..15
    const int sc8  = (lane & 3) * 8;     // 0,8,16,24
    const int row0 = wave * 32 + srow;
    const int row1 = row0 + 16;
    int bn0, bn1;
    if (kk < 2) {
        bn0 = (row0 & 63) * 48 + kk * 16 + cb * 2 + (row0 >> 6);
        bn1 = (row1 & 63) * 48 + kk * 16 + cb * 2 + (row1 >> 6);
    } else {
        bn0 = (cb * 8 + (row0 >> 4)) * 48 + 32 + (row0 & 15);
        bn1 = (cb * 8 + (row1 >> 4)) * 48 + 32 + (row1 & 15);
    }

    floatx4 acc[4][4];
#pragma unroll
    for (int i = 0; i < 4; i++)
#pragma unroll
        for (int j = 0; j < 4; j++) acc[i][j] = (floatx4){0.f, 0.f, 0.f, 0.f};

#define QKV_STAGE(BUF, K0)                                                        \
    do {                                                                          \
        GLD16(&x[(m0 + row0) * 1024 + (K0) + sc8],                                \
              &SM[(BUF) * 8192 + (wave * 32) * 32]);                              \
        GLD16(&x[(m0 + row1) * 1024 + (K0) + sc8],                                \
              &SM[(BUF) * 8192 + (wave * 32 + 16) * 32]);                         \
        GLD16(&wq[bn0 * 1024 + (K0) + sc8],                                       \
              &SM[(BUF) * 8192 + 4096 + (wave * 32) * 32]);                       \
        GLD16(&wq[bn1 * 1024 + (K0) + sc8],                                       \
              &SM[(BUF) * 8192 + 4096 + (wave * 32 + 16) * 32]);                  \
    } while (0)

    QKV_STAGE(0, 0);
    int buf = 0;
    for (int k0 = 0; k0 < 1024; k0 += 32) {
        __syncthreads();
        if (k0 + 32 < 1024) QKV_STAGE(buf ^ 1, k0 + 32);

        const unsigned short* Ab = &SM[buf * 8192];
        const unsigned short* Bb = Ab + 4096;
        short8 af[4], bfv[4];
#pragma unroll
        for (int mi = 0; mi < 4; mi++)
            af[mi] = *(const short8*)&Ab[(wm * 64 + mi * 16 + l16) * 32 + quad * 8];
#pragma unroll
        for (int ni = 0; ni < 4; ni++)
            bfv[ni] = *(const short8*)&Bb[(wn * 64 + ni * 16 + l16) * 32 + quad * 8];
#pragma unroll
        for (int mi = 0; mi < 4; mi++)
#pragma unroll
            for (int ni = 0; ni < 4; ni++)
                acc[mi][ni] = mfma16(af[mi], bfv[ni], acc[mi][ni]);
        buf ^= 1;
    }
    __syncthreads();

    if (kk == 2) {
#pragma unroll
        for (int ni = 0; ni < 4; ni++) {
            const int d = cb * 8 + wn * 4 + ni;
#pragma unroll
            for (int mi = 0; mi < 4; mi++) {
                const int m  = m0 + wm * 64 + mi * 16 + quad * 4;
                const int b  = m >> 11;
                const int tt = m & 2047;
                ushort4 pk;
                pk.x = f2bf_bits(acc[mi][ni][0]);
                pk.y = f2bf_bits(acc[mi][ni][1]);
                pk.z = f2bf_bits(acc[mi][ni][2]);
                pk.w = f2bf_bits(acc[mi][ni][3]);
                *(ushort4*)&vb[((b * 16 + l16) * 64 + d) * 2048 + tt] = pk;
            }
        }
    } else {
        const float scale = (kk == 0) ? 0.045084220027780106f : 1.0f;  // log2(e)/32
        unsigned short* dst = (kk == 0) ? qb : kb;
        const int b = m0 >> 11, tt0 = m0 & 2047;
#pragma unroll
        for (int s = 0; s < 2; s++) {
            if (wn == s) {
#pragma unroll
                for (int ni = 0; ni < 4; ni++) {
                    const int d = ni * 16 + l16;
#pragma unroll
                    for (int mi = 0; mi < 4; mi++) {
                        const int tl = wm * 64 + mi * 16 + quad * 4;
#pragma unroll
                        for (int r = 0; r < 4; r++)
                            SM[(tl + r) * 72 + d] = f2bf_bits(acc[mi][ni][r] * scale);
                    }
                }
            }
            __syncthreads();
#pragma unroll
            for (int u = 0; u < 4; u++) {
                const int w  = tid + u * 256;
                const int tl = w >> 3;
                const int ch = (w & 7) * 8;
                *(uint4*)&dst[((b * 16 + cb * 2 + s) * 2048 + tt0 + tl) * 64 + ch] =
                    *(const uint4*)&SM[tl * 72 + ch];
            }
            __syncthreads();
        }
    }
#undef QKV_STAGE
}

// ---------------------------------------------------------------------------
// Kernel 2: flash attention — round-8 version (best measured: 82.5 µs;
// cross-tile pipeline, 4-buffer LDS, in-register softmax).
// ---------------------------------------------------------------------------
__global__ __launch_bounds__(256, 2) void k_attn(
    const unsigned short* __restrict__ qt,  // [64][2048][64]  (bh, t, d)
    const unsigned short* __restrict__ kt,  // [64][2048][64]
    const unsigned short* __restrict__ vg,  // [64][64][2048]  (bh, d, t)
    __hip_bfloat16* __restrict__ og)        // [4][2048][1024]
{
    __shared__ unsigned short Ks[4 * 4608];  // [buf][key][d]   36864 B
    __shared__ unsigned short Vt[4 * 4608];  // [buf][d][key]   36864 B

    const int tid  = threadIdx.x;
    const int wave = tid >> 6, lane = tid & 63;
    const int l31  = lane & 31, hi = lane >> 5;
    const int blk = blockIdx.x;
    const int bh  = (blk & 7) | ((blk >> 6) << 3);  // XCD-affine
    const int q0  = ((blk >> 3) & 7) * 256;
    const int qr  = q0 + wave * 64;

    short8 qf[2][4];
#pragma unroll
    for (int qb2 = 0; qb2 < 2; qb2++)
#pragma unroll
        for (int ks = 0; ks < 4; ks++)
            qf[qb2][ks] = *(const short8*)
                &qt[(bh * 2048 + qr + qb2 * 32 + l31) * 64 + ks * 16 + hi * 8];

    float lsum[2] = {0.f, 0.f};
    floatx16 o[2][2];
#pragma unroll
    for (int qb2 = 0; qb2 < 2; qb2++)
#pragma unroll
        for (int db = 0; db < 2; db++)
#pragma unroll
            for (int r = 0; r < 16; r++) o[qb2][db][r] = 0.f;

    const int sr = tid >> 2, sc = (tid & 3) * 16;
    const unsigned short* kR = &kt[(bh * 2048 + sr) * 64 + sc];  // tile t: +t*4096
    const unsigned short* vR = &vg[(bh * 64 + sr) * 2048 + sc];  // tile t: +t*64

    uint4 rka, rkb, rva, rvb;
#define LOADT(T)                                                   \
    do {                                                           \
        rka = *(const uint4*)&kR[(T) * 4096];                      \
        rkb = *(const uint4*)&kR[(T) * 4096 + 8];                  \
        rva = *(const uint4*)&vR[(T) * 64];                        \
        rvb = *(const uint4*)&vR[(T) * 64 + 8];                    \
    } while (0)
#define WRITET(B)                                                  \
    do {                                                           \
        *(uint4*)&Ks[(B) * 4608 + sr * 72 + sc]     = rka;         \
        *(uint4*)&Ks[(B) * 4608 + sr * 72 + sc + 8] = rkb;         \
        *(uint4*)&Vt[(B) * 4608 + sr * 72 + sc]     = rva;         \
        *(uint4*)&Vt[(B) * 4608 + sr * 72 + sc + 8] = rvb;         \
    } while (0)

#define SOFTMAX(ST, PAF)                                                        \
    do {                                                                        \
        _Pragma("unroll")                                                       \
        for (int qb2 = 0; qb2 < 2; qb2++) {                                     \
            float p[16];                                                        \
            _Pragma("unroll")                                                   \
            for (int r = 0; r < 16; r++) p[r] = fast_exp2((ST)[qb2][r]);        \
            lsum[qb2] += (((p[0] + p[1]) + (p[2] + p[3])) +                     \
                          ((p[4] + p[5]) + (p[6] + p[7]))) +                    \
                         (((p[8] + p[9]) + (p[10] + p[11])) +                   \
                          ((p[12] + p[13]) + (p[14] + p[15])));                 \
            _Pragma("unroll")                                                   \
            for (int hf = 0; hf < 2; hf++) {                                    \
                const int r0 = hf * 8;                                          \
                unsigned c01 = cvt_pk_bf16(p[r0 + 0], p[r0 + 1]);               \
                unsigned c23 = cvt_pk_bf16(p[r0 + 2], p[r0 + 3]);               \
                unsigned c45 = cvt_pk_bf16(p[r0 + 4], p[r0 + 5]);               \
                unsigned c67 = cvt_pk_bf16(p[r0 + 6], p[r0 + 7]);               \
                plane32_swap(c01, c45);                                         \
                plane32_swap(c23, c67);                                         \
                uint4 t4 = {c01, c23, c45, c67};                                \
                (PAF)[qb2][hf] = *reinterpret_cast<short8*>(&t4);               \
            }                                                                   \
        }                                                                       \
    } while (0)

#define PV(PAF, BO, KB2)                                                        \
    do {                                                                        \
        short8 vf[2][2];                                                        \
        _Pragma("unroll")                                                       \
        for (int db = 0; db < 2; db++)                                          \
            _Pragma("unroll")                                                   \
            for (int hf = 0; hf < 2; hf++)                                      \
                vf[db][hf] = *(const short8*)&Vt[(BO) + (db * 32 + l31) * 72 +  \
                                                 (KB2) * 32 + hf * 16 + hi * 8];\
        __builtin_amdgcn_s_setprio(1);                                          \
        _Pragma("unroll")                                                       \
        for (int qb2 = 0; qb2 < 2; qb2++)                                       \
            _Pragma("unroll")                                                   \
            for (int db = 0; db < 2; db++)                                      \
                _Pragma("unroll")                                               \
                for (int hf = 0; hf < 2; hf++)                                  \
                    o[qb2][db] = mfma32((PAF)[qb2][hf], vf[db][hf], o[qb2][db]);\
        __builtin_amdgcn_s_setprio(0);                                          \
    } while (0)

#define QK(ST, BO, KB2)                                                         \
    do {                                                                        \
        short8 kf[4];                                                           \
        _Pragma("unroll")                                                       \
        for (int ks = 0; ks < 4; ks++)                                          \
            kf[ks] = *(const short8*)&Ks[(BO) + ((KB2) * 32 + l31) * 72 +       \
                                         ks * 16 + hi * 8];                     \
        _Pragma("unroll")                                                       \
        for (int qb2 = 0; qb2 < 2; qb2++)                                       \
            _Pragma("unroll")                                                   \
            for (int r = 0; r < 16; r++) (ST)[qb2][r] = 0.f;                    \
        __builtin_amdgcn_s_setprio(1);                                          \
        _Pragma("unroll")                                                       \
        for (int ks = 0; ks < 4; ks++)                                          \
            _Pragma("unroll")                                                   \
            for (int qb2 = 0; qb2 < 2; qb2++)                                   \
                (ST)[qb2] = mfma32(kf[ks], qf[qb2][ks], (ST)[qb2]);             \
        __builtin_amdgcn_s_setprio(0);                                          \
    } while (0)

    LOADT(0);
    WRITET(0);
    LOADT(1);
    WRITET(1);
    LOADT(2);
    asm volatile("s_waitcnt lgkmcnt(0)" ::: "memory");
    __builtin_amdgcn_s_barrier();
    __builtin_amdgcn_sched_barrier(0);

    floatx16 stP[2];
    QK(stP, 0, 0);

    for (int j = 0; j < 32; ++j) {
        const int bj  = (j & 3) * 4608;
        const int bj1 = ((j + 1) & 3) * 4608;
        if (j <= 29) WRITET((j + 2) & 3);
        if (j <= 28) LOADT(j + 3);

        floatx16 stN[2];
        QK(stN, bj, 1);
        short8 pafP[2][2];
        SOFTMAX(stP, pafP);
        PV(pafP, bj, 0);

        if (j <= 30) QK(stP, bj1, 0);
        short8 pafN[2][2];
        SOFTMAX(stN, pafN);
        PV(pafN, bj, 1);

        asm volatile("s_waitcnt lgkmcnt(0)" ::: "memory");
        __builtin_amdgcn_s_barrier();
        __builtin_amdgcn_sched_barrier(0);
    }
#undef QK
#undef PV
#undef SOFTMAX
#undef WRITET
#undef LOADT

    lsum[0] += __shfl_xor(lsum[0], 32);
    lsum[1] += __shfl_xor(lsum[1], 32);

    const int b = bh >> 4, h = bh & 15;
#pragma unroll
    for (int qb2 = 0; qb2 < 2; qb2++) {
#pragma unroll
        for (int r = 0; r < 16; r++) {
            const int qrl = (r & 3) + 8 * (r >> 2) + 4 * hi;
            const float inv = 1.0f / __shfl(lsum[qb2], qrl);
            const int t = qr + qb2 * 32 + qrl;
#pragma unroll
            for (int db = 0; db < 2; db++)
                og[(b * 2048 + t) * 1024 + h * 64 + db * 32 + l31] =
                    __float2bfloat16(o[qb2][db][r] * inv);
        }
    }
}

// ---------------------------------------------------------------------------
// Kernel 3: output projection — r2-verified 128² 2-phase dbuf, natural VGPR.
// ---------------------------------------------------------------------------
__global__ __launch_bounds__(256) void k_out(
    const unsigned short* __restrict__ a,    // [8192][1024] bf16
    const unsigned short* __restrict__ wq,   // [1024][1024] bf16
    const float* __restrict__ bias,
    float* __restrict__ out)                 // [8192][1024] fp32
{
    __shared__ unsigned short SM[16384];

    const int tid  = threadIdx.x;
    const int wave = tid >> 6, lane = tid & 63;
    const int quad = lane >> 4, l16 = lane & 15;
    const int wm = wave >> 1, wn = wave & 1;

    const int fid  = blockIdx.y * 8 + blockIdx.x;
    const int nfid = (fid & 7) * 64 + (fid >> 3);
    const int n0 = (nfid & 7) * 128;
    const int m0 = (nfid >> 3) * 128;

    const int srow = lane >> 2;
    const int sc8  = (lane & 3) * 8;
    const int row0 = wave * 32 + srow;
    const int row1 = row0 + 16;

    floatx4 acc[4][4];
#pragma unroll
    for (int i = 0; i < 4; i++)
#pragma unroll
        for (int j = 0; j < 4; j++) acc[i][j] = (floatx4){0.f, 0.f, 0.f, 0.f};

#define OUT_STAGE(BUF, K0)                                                        \
    do {                                                                          \
        GLD16(&a[(m0 + row0) * 1024 + (K0) + sc8],                                \
              &SM[(BUF) * 8192 + (wave * 32) * 32]);                              \
        GLD16(&a[(m0 + row1) * 1024 + (K0) + sc8],                                \
              &SM[(BUF) * 8192 + (wave * 32 + 16) * 32]);                         \
        GLD16(&wq[(n0 + row0) * 1024 + (K0) + sc8],                               \
              &SM[(BUF) * 8192 + 4096 + (wave * 32) * 32]);                       \
        GLD16(&wq[(n0 + row1) * 1024 + (K0) + sc8],                               \
              &SM[(BUF) * 8192 + 4096 + (wave * 32 + 16) * 32]);                  \
    } while (0)

    OUT_STAGE(0, 0);
    int buf = 0;
    for (int k0 = 0; k0 < 1024; k0 += 32) {
        __syncthreads();
        if (k0 + 32 < 1024) OUT_STAGE(buf ^ 1, k0 + 32);

        const unsigned short* Ab = &SM[buf * 8192];
        const unsigned short* Bb = Ab + 4096;
        short8 af[4], bfv[4];
#pragma unroll
        for (int mi = 0; mi < 4; mi++)
            af[mi] = *(const short8*)&Ab[(wm * 64 + mi * 16 + l16) * 32 + quad * 8];
#pragma unroll
        for (int ni = 0; ni < 4; ni++)
            bfv[ni] = *(const short8*)&Bb[(wn * 64 + ni * 16 + l16) * 32 + quad * 8];
#pragma unroll
        for (int mi = 0; mi < 4; mi++)
#pragma unroll
            for (int ni = 0; ni < 4; ni++)
                acc[mi][ni] = mfma16(af[mi], bfv[ni], acc[mi][ni]);
        buf ^= 1;
    }
#undef OUT_STAGE

#pragma unroll
    for (int ni = 0; ni < 4; ni++) {
        const int col = n0 + wn * 64 + ni * 16 + l16;
        const float bv = bias[col];
#pragma unroll
        for (int mi = 0; mi < 4; mi++) {
            const int mbase = m0 + wm * 64 + mi * 16 + quad * 4;
#pragma unroll
            for (int r = 0; r < 4; r++)
                out[(mbase + r) * 1024 + col] = acc[mi][ni][r] + bv;
        }
    }
}

// ---------------------------------------------------------------------------
extern "C" void kernel_launch(void* const* d_in, const int* in_sizes, int n_in,
                              void* d_out, int out_size, void* d_ws, size_t ws_size,
                              hipStream_t stream) {
    const float* x    = (const float*)d_in[0];
    const float* wqkv = (const float*)d_in[1];
    const float* wout = (const float*)d_in[2];
    const float* bout = (const float*)d_in[3];
    float* out = (float*)d_out;

    unsigned short* ws = (unsigned short*)d_ws;
    unsigned short* xb    = ws;                  // x bf16
    unsigned short* wqkvb = xb + 8388608;
    unsigned short* woutb = wqkvb + 3145728;
    unsigned short* qb    = woutb + 1048576;     // q [bh][t][d]
    unsigned short* kb    = qb + 8388608;        // k [bh][t][d]
    unsigned short* vb    = kb + 8388608;        // v [bh][d][t]
    unsigned short* ob    = vb + 8388608;        // attn out

    k_cvt<<<2048, 256, 0, stream>>>(x,    xb,    8388608 / 4);
    k_cvt<<<1024, 256, 0, stream>>>(wqkv, wqkvb, 3145728 / 4);
    k_cvt<<<512,  256, 0, stream>>>(wout, woutb, 1048576 / 4);

    k_qkv<<<dim3(24, 64), 256, 0, stream>>>(xb, wqkvb, qb, kb, vb);
    k_attn<<<512, 256, 0, stream>>>(qb, kb, vb, (__hip_bfloat16*)ob);
    k_out<<<dim3(8, 64), 256, 0, stream>>>(ob, woutb, bout, out);
}